// Round 14
// baseline (51.386 us; speedup 1.0000x reference)
//
#include <hip/hip_runtime.h>
#include <cstdint>

namespace {

constexpr int NB = 320;   // batch
constexpr int ND = 128;   // feature dim
constexpr int NC = 80;    // label dim
constexpr int NANCH = 30;
constexpr int NW = 5;     // 64-bit words per 320-bit row

// ---- workspace layout (byte offsets) ----
constexpr size_t OFF_DIV  = 0;        // float[320]
constexpr size_t OFF_ASUM = 1280;     // double[320]
constexpr size_t OFF_ACNT = 3840;     // int[320]
constexpr size_t OFF_PACK = 5120;     // u64[640]
constexpr size_t OFF_TGTT = 10240;    // float2[64][320] = 163840 B

// K0: transpose tgt + pack labels (verbatim R10 31.3us lineage).
__global__ __launch_bounds__(256) void k_prep(
    const float* __restrict__ tgt,
    const int* __restrict__ label,
    float2* __restrict__ tgtT2,
    unsigned long long* __restrict__ packed)
{
    const int tid = threadIdx.x;
    const int w = tid >> 6, lane = tid & 63;
    const int r0 = blockIdx.x * 64;            // 5 blocks x 64 rows

    __shared__ float tile[64][133];

    if (w == 0) {
        const int r = r0 + lane;
        const int4* lp = reinterpret_cast<const int4*>(label + r * NC);
        unsigned long long j0 = 0, j1 = 0;
#pragma unroll
        for (int q = 0; q < 16; ++q) {
            int4 v = lp[q];
            j0 |= (unsigned long long)(v.x != 0) << (4 * q + 0);
            j0 |= (unsigned long long)(v.y != 0) << (4 * q + 1);
            j0 |= (unsigned long long)(v.z != 0) << (4 * q + 2);
            j0 |= (unsigned long long)(v.w != 0) << (4 * q + 3);
        }
#pragma unroll
        for (int q = 16; q < 20; ++q) {
            int4 v = lp[q];
            const int b = 4 * (q - 16);
            j1 |= (unsigned long long)(v.x != 0) << (b + 0);
            j1 |= (unsigned long long)(v.y != 0) << (b + 1);
            j1 |= (unsigned long long)(v.z != 0) << (b + 2);
            j1 |= (unsigned long long)(v.w != 0) << (b + 3);
        }
        packed[2 * r]     = j0;
        packed[2 * r + 1] = j1;
    }

#pragma unroll
    for (int it = 0; it < 8; ++it) {
        const int f4 = it * 256 + tid;
        float4 v = reinterpret_cast<const float4*>(tgt)[r0 * (ND / 4) + f4];
        const int r = f4 >> 5, d4 = (f4 & 31) << 2;
        tile[r][d4 + 0] = v.x; tile[r][d4 + 1] = v.y;
        tile[r][d4 + 2] = v.z; tile[r][d4 + 3] = v.w;
    }
    __syncthreads();

#pragma unroll
    for (int it = 0; it < 16; ++it) {
        const int d2 = it * 4 + w;
        float2 o;
        o.x = tile[lane][2 * d2 + 0];
        o.y = tile[lane][2 * d2 + 1];
        tgtT2[d2 * NB + r0 + lane] = o;
    }
}

// K1: verbatim R10 k_main (absmax-0.0 lineage).
__global__ __launch_bounds__(256) void k_main(
    const float* __restrict__ src,
    const float2* __restrict__ tgtT2,
    const unsigned long long* __restrict__ packed,
    float* __restrict__ divr,
    double* __restrict__ asum,
    int* __restrict__ acnt)
{
    const int a = blockIdx.x;
    const int tid = threadIdx.x;
    const int w = tid >> 6, lane = tid & 63;

    __shared__ float sa[ND];
    __shared__ float snsa;
    __shared__ float red[256];
    __shared__ unsigned long long pk[2 * NB];
    __shared__ float fdrow[NB];
    __shared__ unsigned long long pmask[NW], nmask[NW];
    __shared__ double wsum[4];

    if (tid < ND) sa[tid] = src[a * ND + tid];
    if (w == 0) {
        float s0 = src[a * ND + lane];
        float s1 = src[a * ND + lane + 64];
        float v = s0 * s0 + s1 * s1;
        for (int off = 32; off > 0; off >>= 1) v += __shfl_down(v, off);
        if (lane == 0) snsa = sqrtf(v);
    }
    for (int q = tid; q < 2 * NB; q += 256) pk[q] = packed[q];
    __syncthreads();

    const unsigned long long a0 = pk[2 * a], a1 = pk[2 * a + 1];
    const float nsa = snsa;

    float acc = 0.f;
#pragma unroll
    for (int it = 0; it < 2; ++it) {
        const int j = tid + 256 * it;
        if (j < NB) {
            float dot = 0.f, tn = 0.f;
#pragma unroll
            for (int d = 0; d < ND / 4; ++d) {
                float2 u = tgtT2[(2 * d + 0) * NB + j];
                float2 v = tgtT2[(2 * d + 1) * NB + j];
                dot += sa[4 * d + 0] * u.x + sa[4 * d + 1] * u.y +
                       sa[4 * d + 2] * v.x + sa[4 * d + 3] * v.y;
                tn += u.x * u.x + u.y * u.y + v.x * v.x + v.y * v.y;
            }
            float sim = dot / fmaxf(nsa * sqrtf(tn), 1e-8f);
            float f = fmaxf(1.0f - sim, 0.0f);
            fdrow[j] = f;
            acc += f;
        }
    }

    red[tid] = acc;
    __syncthreads();
    for (int st = 128; st > 0; st >>= 1) {
        if (tid < st) red[tid] += red[tid + st];
        __syncthreads();
    }
    if (tid == 0) divr[a] = red[0] / (float)NB;

    const float sna = sqrtf((float)(__popcll(a0) + __popcll(a1)));
#pragma unroll
    for (int it = 0; it < 2; ++it) {
        const int jj = tid + 256 * it;
        if (jj < NB) {
            const unsigned long long j0 = pk[2 * jj], j1 = pk[2 * jj + 1];
            const float snj = sqrtf((float)(__popcll(j0) + __popcll(j1)));
            const float denom = sna * snj;
            const float dotf = (float)(__popcll(a0 & j0) + __popcll(a1 & j1));
            const float ld = 1.0f - fminf(1.0f, dotf / denom);
            const bool valid = (jj != a) && (denom > 0.f);
            unsigned long long pb = __ballot(valid && (ld <= 0.2f));
            unsigned long long nb = __ballot(valid && (ld >= 0.5f));
            if (lane == 0) { pmask[jj >> 6] = pb; nmask[jj >> 6] = nb; }
        }
    }
    __syncthreads();

    double s = 0.0;
#pragma unroll
    for (int it = 0; it < 2; ++it) {
        const int jj = tid + 256 * it;
        if (jj < NB && ((nmask[jj >> 6] >> (jj & 63)) & 1ull)) {
            const float fn = fdrow[jj];
#pragma unroll
            for (int wd = 0; wd < NW; ++wd) {
                unsigned long long m = pmask[wd];
                while (m) {
                    const int b = __builtin_ctzll(m);
                    m &= m - 1;
                    float v = fdrow[wd * 64 + b] - fn + 0.5f;
                    if (v > 0.f) s += (double)v;
                }
            }
        }
    }
    for (int off = 32; off > 0; off >>= 1) s += __shfl_down(s, off);
    if (lane == 0) wsum[w] = s;
    __syncthreads();
    if (tid == 0) {
        int P = 0, N = 0;
#pragma unroll
        for (int wd = 0; wd < NW; ++wd) {
            P += __popcll(pmask[wd]);
            N += __popcll(nmask[wd]);
        }
        asum[a] = wsum[0] + wsum[1] + wsum[2] + wsum[3];
        acnt[a] = P * N;
    }
}

// K2: verbatim R10 k_final.
__global__ __launch_bounds__(320) void k_final(
    const float* __restrict__ divr,
    const double* __restrict__ asum,
    const int* __restrict__ acnt,
    float* __restrict__ out)
{
    const int tid = threadIdx.x;
    __shared__ float dv[NB];
    __shared__ int alist[NANCH];
    __shared__ double sl[NANCH];
    __shared__ int cl[NANCH];

    dv[tid] = divr[tid];
    __syncthreads();

    const float ve = dv[tid];
    int rank = 0;
#pragma unroll 8
    for (int j = 0; j < NB; ++j) {
        float vj = dv[j];
        rank += (vj > ve) || (vj == ve && j < tid);
    }
    if (rank < NANCH) alist[rank] = tid;
    __syncthreads();

    if (tid < NANCH) {
        sl[tid] = asum[alist[tid]];
        cl[tid] = acnt[alist[tid]];
    }
    __syncthreads();
    if (tid == 0) {
        double S = 0.0;
        long long C = 0;
        for (int r = 0; r < NANCH; ++r) { S += sl[r]; C += cl[r]; }
        out[0] = (float)(S / ((double)C + 1e-4));
    }
}

} // namespace

extern "C" void kernel_launch(void* const* d_in, const int* in_sizes, int n_in,
                              void* d_out, int out_size, void* d_ws, size_t ws_size,
                              hipStream_t stream) {
    const int* label = (const int*)d_in[0];
    const float* src = (const float*)d_in[1];
    const float* tgt = (const float*)d_in[2];

    char* ws = (char*)d_ws;
    float* divr  = (float*)(ws + OFF_DIV);
    double* asum = (double*)(ws + OFF_ASUM);
    int* acnt    = (int*)(ws + OFF_ACNT);
    unsigned long long* packed = (unsigned long long*)(ws + OFF_PACK);
    float2* tgtT2 = (float2*)(ws + OFF_TGTT);

    // MEASUREMENT ROUND: R10 chain with k_main replayed 3x (idempotent).
    // dur = R10_dur + 2 * t_main  -> directly pins k_main's cost.
    k_prep <<<5, 256, 0, stream>>>(tgt, label, tgtT2, packed);
    k_main <<<NB, 256, 0, stream>>>(src, tgtT2, packed, divr, asum, acnt);
    k_main <<<NB, 256, 0, stream>>>(src, tgtT2, packed, divr, asum, acnt);
    k_main <<<NB, 256, 0, stream>>>(src, tgtT2, packed, divr, asum, acnt);
    k_final<<<1, 320, 0, stream>>>(divr, asum, acnt, (float*)d_out);
}

// Round 15
// 29.670 us; speedup vs baseline: 1.7319x; 1.7319x over previous
//
#include <hip/hip_runtime.h>
#include <cstdint>

namespace {

constexpr int NB = 320;   // batch
constexpr int ND = 128;   // feature dim
constexpr int NC = 80;    // label dim
constexpr int NANCH = 30;
constexpr int NW = 5;     // 64-bit words per 320-bit row

// ---- workspace layout (byte offsets) ----
constexpr size_t OFF_DIV  = 0;        // float[320]
constexpr size_t OFF_ASUM = 1280;     // double[320]
constexpr size_t OFF_ACNT = 3840;     // int[320]
constexpr size_t OFF_PACK = 5120;     // u64[640]
constexpr size_t OFF_TGTT = 10240;    // float4[32][320] = 163840 B

// K0: 40 blocks x 8 rows. Label packing: coalesced lane-reads + ballots
// (no strided gathers). Transpose: 1 float4 load + 1 float4 store per thread.
__global__ __launch_bounds__(256) void k_prep(
    const float* __restrict__ tgt,
    const int* __restrict__ label,
    float4* __restrict__ tgtT4,
    unsigned long long* __restrict__ packed)
{
    const int tid = threadIdx.x;
    const int w = tid >> 6, lane = tid & 63;
    const int r0 = blockIdx.x * 8;             // 40 blocks x 8 rows

    __shared__ float4 tile4[8][33];            // pad col -> spread banks

    // ---- label packing: wave w packs rows r0+w and r0+4+w (coalesced) ----
    {
        const int r = r0 + w;
        int l0 = label[r * NC + lane];
        int l1 = (lane < NC - 64) ? label[r * NC + 64 + lane] : 0;
        unsigned long long b0 = __ballot(l0 != 0);
        unsigned long long b1 = __ballot(l1 != 0);
        if (lane == 0) { packed[2 * r] = b0; packed[2 * r + 1] = b1; }

        const int r2 = r0 + 4 + w;
        l0 = label[r2 * NC + lane];
        l1 = (lane < NC - 64) ? label[r2 * NC + 64 + lane] : 0;
        b0 = __ballot(l0 != 0);
        b1 = __ballot(l1 != 0);
        if (lane == 0) { packed[2 * r2] = b0; packed[2 * r2 + 1] = b1; }
    }

    // ---- transpose 8x128 slab: fully coalesced both sides ----
    {
        const int r = tid >> 5, d4 = tid & 31;           // 8 rows x 32 float4
        tile4[r][d4] = reinterpret_cast<const float4*>(tgt)[(r0 + r) * 32 + d4];
    }
    __syncthreads();
    {
        const int rr = tid & 7, d4 = tid >> 3;           // 32 d4 x 8 rows
        tgtT4[d4 * NB + r0 + rr] = tile4[rr][d4];
    }
}

// K1: verbatim R10 k_main except fd loads are float4 (same elements, same
// expression order -> bit-exact vs the absmax-0.0 lineage).
__global__ __launch_bounds__(256) void k_main(
    const float* __restrict__ src,
    const float4* __restrict__ tgtT4,
    const unsigned long long* __restrict__ packed,
    float* __restrict__ divr,
    double* __restrict__ asum,
    int* __restrict__ acnt)
{
    const int a = blockIdx.x;
    const int tid = threadIdx.x;
    const int w = tid >> 6, lane = tid & 63;

    __shared__ float sa[ND];
    __shared__ float snsa;
    __shared__ float red[256];
    __shared__ unsigned long long pk[2 * NB];
    __shared__ float fdrow[NB];
    __shared__ unsigned long long pmask[NW], nmask[NW];
    __shared__ double wsum[4];

    if (tid < ND) sa[tid] = src[a * ND + tid];
    if (w == 0) {
        float s0 = src[a * ND + lane];
        float s1 = src[a * ND + lane + 64];
        float v = s0 * s0 + s1 * s1;
        for (int off = 32; off > 0; off >>= 1) v += __shfl_down(v, off);
        if (lane == 0) snsa = sqrtf(v);
    }
    for (int q = tid; q < 2 * NB; q += 256) pk[q] = packed[q];
    __syncthreads();

    const unsigned long long a0 = pk[2 * a], a1 = pk[2 * a + 1];
    const float nsa = snsa;

    float acc = 0.f;
#pragma unroll
    for (int it = 0; it < 2; ++it) {
        const int j = tid + 256 * it;
        if (j < NB) {
            float dot = 0.f, tn = 0.f;
#pragma unroll
            for (int d = 0; d < ND / 4; ++d) {
                float4 t = tgtT4[d * NB + j];
                dot += sa[4 * d + 0] * t.x + sa[4 * d + 1] * t.y +
                       sa[4 * d + 2] * t.z + sa[4 * d + 3] * t.w;
                tn += t.x * t.x + t.y * t.y + t.z * t.z + t.w * t.w;
            }
            float sim = dot / fmaxf(nsa * sqrtf(tn), 1e-8f);
            float f = fmaxf(1.0f - sim, 0.0f);
            fdrow[j] = f;
            acc += f;
        }
    }

    red[tid] = acc;
    __syncthreads();
    for (int st = 128; st > 0; st >>= 1) {
        if (tid < st) red[tid] += red[tid + st];
        __syncthreads();
    }
    if (tid == 0) divr[a] = red[0] / (float)NB;

    const float sna = sqrtf((float)(__popcll(a0) + __popcll(a1)));
#pragma unroll
    for (int it = 0; it < 2; ++it) {
        const int jj = tid + 256 * it;
        if (jj < NB) {
            const unsigned long long j0 = pk[2 * jj], j1 = pk[2 * jj + 1];
            const float snj = sqrtf((float)(__popcll(j0) + __popcll(j1)));
            const float denom = sna * snj;
            const float dotf = (float)(__popcll(a0 & j0) + __popcll(a1 & j1));
            const float ld = 1.0f - fminf(1.0f, dotf / denom);
            const bool valid = (jj != a) && (denom > 0.f); // 0-label -> NaN in ref -> excluded
            unsigned long long pb = __ballot(valid && (ld <= 0.2f));
            unsigned long long nb = __ballot(valid && (ld >= 0.5f));
            if (lane == 0) { pmask[jj >> 6] = pb; nmask[jj >> 6] = nb; }
        }
    }
    __syncthreads();

    double s = 0.0;
#pragma unroll
    for (int it = 0; it < 2; ++it) {
        const int jj = tid + 256 * it;
        if (jj < NB && ((nmask[jj >> 6] >> (jj & 63)) & 1ull)) {
            const float fn = fdrow[jj];
#pragma unroll
            for (int wd = 0; wd < NW; ++wd) {
                unsigned long long m = pmask[wd];
                while (m) {
                    const int b = __builtin_ctzll(m);
                    m &= m - 1;
                    float v = fdrow[wd * 64 + b] - fn + 0.5f;
                    if (v > 0.f) s += (double)v;
                }
            }
        }
    }
    for (int off = 32; off > 0; off >>= 1) s += __shfl_down(s, off);
    if (lane == 0) wsum[w] = s;
    __syncthreads();
    if (tid == 0) {
        int P = 0, N = 0;
#pragma unroll
        for (int wd = 0; wd < NW; ++wd) {
            P += __popcll(pmask[wd]);
            N += __popcll(nmask[wd]);
        }
        asum[a] = wsum[0] + wsum[1] + wsum[2] + wsum[3];
        acnt[a] = P * N;
    }
}

// K2: verbatim R10 k_final.
__global__ __launch_bounds__(320) void k_final(
    const float* __restrict__ divr,
    const double* __restrict__ asum,
    const int* __restrict__ acnt,
    float* __restrict__ out)
{
    const int tid = threadIdx.x;
    __shared__ float dv[NB];
    __shared__ int alist[NANCH];
    __shared__ double sl[NANCH];
    __shared__ int cl[NANCH];

    dv[tid] = divr[tid];
    __syncthreads();

    const float ve = dv[tid];
    int rank = 0;
#pragma unroll 8
    for (int j = 0; j < NB; ++j) {
        float vj = dv[j];
        rank += (vj > ve) || (vj == ve && j < tid);
    }
    if (rank < NANCH) alist[rank] = tid;   // ranks unique; = lax.top_k order
    __syncthreads();

    if (tid < NANCH) {
        sl[tid] = asum[alist[tid]];
        cl[tid] = acnt[alist[tid]];
    }
    __syncthreads();
    if (tid == 0) {
        double S = 0.0;
        long long C = 0;
        for (int r = 0; r < NANCH; ++r) { S += sl[r]; C += cl[r]; }
        out[0] = (float)(S / ((double)C + 1e-4));
    }
}

} // namespace

extern "C" void kernel_launch(void* const* d_in, const int* in_sizes, int n_in,
                              void* d_out, int out_size, void* d_ws, size_t ws_size,
                              hipStream_t stream) {
    const int* label = (const int*)d_in[0];
    const float* src = (const float*)d_in[1];
    const float* tgt = (const float*)d_in[2];

    char* ws = (char*)d_ws;
    float* divr  = (float*)(ws + OFF_DIV);
    double* asum = (double*)(ws + OFF_ASUM);
    int* acnt    = (int*)(ws + OFF_ACNT);
    unsigned long long* packed = (unsigned long long*)(ws + OFF_PACK);
    float4* tgtT4 = (float4*)(ws + OFF_TGTT);

    k_prep <<<40, 256, 0, stream>>>(tgt, label, tgtT4, packed);
    k_main <<<NB, 256, 0, stream>>>(src, tgtT4, packed, divr, asum, acnt);
    k_final<<<1, 320, 0, stream>>>(divr, asum, acnt, (float*)d_out);
}